// Round 5
// baseline (284.738 us; speedup 1.0000x reference)
//
#include <hip/hip_runtime.h>
#include <hip/hip_bf16.h>

#define N_G   2048
#define IMGF  128.0f
#define RECF  12         // floats per gaussian record (3 x float4, 48 B)

// record layout:
//  [0..3] = {mu_x, mu_y, A2, B2}
//  [4..7] = {D2,   L,    cr, cg}
//  [8]    = cb   (9..11 pad)
// p2 = A2*dx^2 + B2*dx*dy + D2*dy^2 + L ;  alpha = min(exp2(p2), 0.99)
// L = log2(opacity) or -1e10 if invalid (exp2 -> 0 reproduces valid-mask)

__global__ void gs_preprocess(const float* __restrict__ means,
                              const float* __restrict__ log_scales,
                              const float* __restrict__ rotations,
                              const float* __restrict__ opacity_logit,
                              const float* __restrict__ color_pre,
                              const float* __restrict__ cam_pos,
                              const float* __restrict__ look_at,
                              float* __restrict__ rec,
                              float* __restrict__ depth)
{
    int i = blockIdx.x * blockDim.x + threadIdx.x;
    if (i >= N_G) return;

    // ---- camera basis (uniform, cheap to recompute per thread) ----
    float cx = cam_pos[0], cy = cam_pos[1], cz = cam_pos[2];
    float fx = look_at[0] - cx, fy = look_at[1] - cy, fz = look_at[2] - cz;
    float fn = 1.0f / sqrtf(fx*fx + fy*fy + fz*fz);
    fx *= fn; fy *= fn; fz *= fn;
    float rx = -fz, ry = 0.0f, rz = fx;                 // cross(fwd,(0,1,0))
    float rn = 1.0f / sqrtf(rx*rx + ry*ry + rz*rz);
    rx *= rn; ry *= rn; rz *= rn;
    float ux = ry*fz - rz*fy, uy = rz*fx - rx*fz, uz = rx*fy - ry*fx;

    // ---- project mean ----
    float mx = means[3*i+0] - cx, my = means[3*i+1] - cy, mz = means[3*i+2] - cz;
    float m0 =  rx*mx + ry*my + rz*mz;
    float m1 =  ux*mx + uy*my + uz*mz;
    float m2 = -(fx*mx + fy*my + fz*mz);
    float d  = -m2;
    float invz = 1.0f / (-m2 + 1e-8f);
    float m2dx =  (m0 * invz) * IMGF + IMGF * 0.5f;
    float m2dy = -(m1 * invz) * IMGF + IMGF * 0.5f;

    // ---- cov3d = R diag(s^2) R^T ----
    float s0 = expf(log_scales[3*i+0]);
    float s1 = expf(log_scales[3*i+1]);
    float s2 = expf(log_scales[3*i+2]);
    float qw = rotations[4*i+0], qx = rotations[4*i+1],
          qy = rotations[4*i+2], qz = rotations[4*i+3];
    float qn = 1.0f / sqrtf(qw*qw + qx*qx + qy*qy + qz*qz);
    qw *= qn; qx *= qn; qy *= qn; qz *= qn;
    float R00 = 1-2*(qy*qy+qz*qz), R01 = 2*(qx*qy-qw*qz), R02 = 2*(qx*qz+qw*qy);
    float R10 = 2*(qx*qy+qw*qz), R11 = 1-2*(qx*qx+qz*qz), R12 = 2*(qy*qz-qw*qx);
    float R20 = 2*(qx*qz-qw*qy), R21 = 2*(qy*qz+qw*qx), R22 = 1-2*(qx*qx+qy*qy);
    float t0 = s0*s0, t1 = s1*s1, t2 = s2*s2;
    float C00 = R00*R00*t0 + R01*R01*t1 + R02*R02*t2;
    float C01 = R00*R10*t0 + R01*R11*t1 + R02*R12*t2;
    float C02 = R00*R20*t0 + R01*R21*t1 + R02*R22*t2;
    float C11 = R10*R10*t0 + R11*R11*t1 + R12*R12*t2;
    float C12 = R10*R20*t0 + R11*R21*t1 + R12*R22*t2;
    float C22 = R20*R20*t0 + R21*R21*t1 + R22*R22*t2;

    // ---- cov_cam 2x2 (rows: right, up) ----
    float v0 = C00*rx + C01*ry + C02*rz;
    float v1 = C01*rx + C11*ry + C12*rz;
    float v2 = C02*rx + C12*ry + C22*rz;
    float ca = rx*v0 + ry*v1 + rz*v2;
    float cb = ux*v0 + uy*v1 + uz*v2;
    float w0 = C00*ux + C01*uy + C02*uz;
    float w1 = C01*ux + C11*uy + C12*uz;
    float w2 = C02*ux + C12*uy + C22*uz;
    float cd = ux*w0 + uy*w1 + uz*w2;

    float z2 = fmaxf(d*d, 0.01f);
    float sc = (IMGF * IMGF) / z2;
    float a  = ca*sc + 0.3f;
    float b  = cb*sc;
    float dd = cd*sc + 0.3f;
    float det  = fmaxf(a*dd - b*b, 1e-6f);
    float idet = 1.0f / det;

    bool valid = (d > 0.1f) && (m2dx > -IMGF) && (m2dx < 2.0f*IMGF)
                            && (m2dy > -IMGF) && (m2dy < 2.0f*IMGF);

    float op = 1.0f / (1.0f + expf(-opacity_logit[i]));
    const float L2E = 1.4426950408889634f;
    float A2 = -0.5f * L2E * dd * idet;
    float B2 =          L2E * b  * idet;
    float D2 = -0.5f * L2E * a  * idet;
    float L  = valid ? log2f(op) : -1e10f;

    float cr = 1.0f / (1.0f + expf(-color_pre[3*i+0]));
    float cg = 1.0f / (1.0f + expf(-color_pre[3*i+1]));
    float cl = 1.0f / (1.0f + expf(-color_pre[3*i+2]));

    float4* r4 = (float4*)(rec + RECF*i);
    r4[0] = make_float4(m2dx, m2dy, A2, B2);
    r4[1] = make_float4(D2, L, cr, cg);
    r4[2] = make_float4(cl, 0.0f, 0.0f, 0.0f);
    depth[i] = d;
}

// O(N^2) stable rank sort, depths staged in LDS (broadcast reads, no global
// latency in the loop). 32 blocks x 64; thread i scatters its record to rank.
__global__ void __launch_bounds__(64)
gs_rank_scatter(const float* __restrict__ depth,
                const float* __restrict__ rec,
                float* __restrict__ srec)
{
    __shared__ float sd[N_G];
    int t = threadIdx.x;
    int i = blockIdx.x * 64 + t;

    const float4* d4 = (const float4*)depth;
    float4* s4 = (float4*)sd;
    #pragma unroll
    for (int q = 0; q < 8; ++q) s4[t + q*64] = d4[t + q*64];   // 8 KB staged
    __syncthreads();

    float di = sd[i & (N_G-1)];
    int rank = 0;
    #pragma unroll 4
    for (int j = 0; j < N_G; j += 4) {
        float4 dj = *(const float4*)(sd + j);
        rank += (dj.x < di) || (dj.x == di && (j+0) < i);
        rank += (dj.y < di) || (dj.y == di && (j+1) < i);
        rank += (dj.z < di) || (dj.z == di && (j+2) < i);
        rank += (dj.w < di) || (dj.w == di && (j+3) < i);
    }
    const float4* s = (const float4*)(rec + RECF*i);
    float4*       o = (float4*)(srec + RECF*rank);
    o[0] = s[0]; o[1] = s[1]; o[2] = s[2];
}

// one thread per pixel; 256 blocks x 64 -> 1 wave/CU on all 256 CUs.
// Records read straight from global with wave-uniform addresses -> scalar
// loads on the SMEM pipe (parallel to VALU), no LDS, no barriers, no
// early-exit branches: one flat unrolled stream the compiler can pipeline.
__global__ void __launch_bounds__(64)
gs_raster(const float* __restrict__ srec, float* __restrict__ out)
{
    int t = threadIdx.x;
    int p = blockIdx.x * 64 + t;
    float px = (float)(p & 127);
    float py = (float)(p >> 7);

    float Ir = 1.0f, Ig = 1.0f, Ib = 1.0f, T = 1.0f;

    #pragma unroll 8
    for (int j = 0; j < N_G; ++j) {
        const float* r = srec + j * RECF;
        float4 ra = *(const float4*)(r);       // mu_x, mu_y, A2, B2
        float4 rb = *(const float4*)(r + 4);   // D2, L, cr, cg
        float cb = r[8];                       // cb
        float dx = px - ra.x;
        float dy = py - ra.y;
        float p2 = fmaf(dx, fmaf(ra.z, dx, ra.w * dy),
                        fmaf(rb.x * dy, dy, rb.y));
        float al = fminf(__builtin_amdgcn_exp2f(p2), 0.99f);
        float w  = T * al;
        Ir = fmaf(w, rb.z - Ir, Ir);
        Ig = fmaf(w, rb.w - Ig, Ig);
        Ib = fmaf(w, cb   - Ib, Ib);
        T -= w;
    }

    float* o = out + p * 3;
    o[0] = fminf(fmaxf(Ir, 0.0f), 1.0f);
    o[1] = fminf(fmaxf(Ig, 0.0f), 1.0f);
    o[2] = fminf(fmaxf(Ib, 0.0f), 1.0f);
}

extern "C" void kernel_launch(void* const* d_in, const int* in_sizes, int n_in,
                              void* d_out, int out_size, void* d_ws, size_t ws_size,
                              hipStream_t stream)
{
    const float* means         = (const float*)d_in[0];
    const float* log_scales    = (const float*)d_in[1];
    const float* rotations     = (const float*)d_in[2];
    const float* opacity_logit = (const float*)d_in[3];
    const float* color_pre     = (const float*)d_in[4];
    const float* cam_pos       = (const float*)d_in[5];
    const float* look_at       = (const float*)d_in[6];
    float* out = (float*)d_out;

    char* ws = (char*)d_ws;
    float* rec   = (float*)(ws);                                     // 2048*12 f
    float* depth = (float*)(ws + N_G * RECF * 4);                    // 2048 f
    float* srec  = (float*)(ws + N_G * RECF * 4 + N_G * 4);          // 2048*12 f

    hipLaunchKernelGGL(gs_preprocess, dim3(N_G / 256), dim3(256), 0, stream,
                       means, log_scales, rotations, opacity_logit, color_pre,
                       cam_pos, look_at, rec, depth);
    hipLaunchKernelGGL(gs_rank_scatter, dim3(N_G / 64), dim3(64), 0, stream,
                       depth, rec, srec);
    hipLaunchKernelGGL(gs_raster, dim3(16384 / 64), dim3(64), 0, stream,
                       srec, out);
}

// Round 6
// 160.362 us; speedup vs baseline: 1.7756x; 1.7756x over previous
//
#include <hip/hip_runtime.h>
#include <hip/hip_bf16.h>
#include <hip/hip_fp16.h>

#define N_G   2048
#define IMGF  128.0f
#define RECF  8          // floats per gaussian record (2 x float4, 32 B)

// record layout (8 floats):
//  [0]=mu_x [1]=mu_y [2]=A2 [3]=B2 [4]=D2 [5]=L [6]=f16pack(cr,cg) [7]=f16pack(cb,0)
// p2 = A2*dx^2 + B2*dx*dy + D2*dy^2 + L ; alpha = min(exp2(p2), 0.99)
// L = log2(opacity) or -1e10 if invalid (exp2 -> 0 reproduces valid-mask)
//
// Sorted storage is ITERATION-MAJOR: rank r lives at slot (r&31)*64 + (r>>5),
// so at inner step i the wave's 64 lanes read 64 adjacent records (coalesced)
// while lane l owns the contiguous rank range [32l, 32l+32) (scan order).

__global__ void gs_preprocess(const float* __restrict__ means,
                              const float* __restrict__ log_scales,
                              const float* __restrict__ rotations,
                              const float* __restrict__ opacity_logit,
                              const float* __restrict__ color_pre,
                              const float* __restrict__ cam_pos,
                              const float* __restrict__ look_at,
                              float* __restrict__ rec,
                              float* __restrict__ depth)
{
    int i = blockIdx.x * blockDim.x + threadIdx.x;
    if (i >= N_G) return;

    float cx = cam_pos[0], cy = cam_pos[1], cz = cam_pos[2];
    float fx = look_at[0] - cx, fy = look_at[1] - cy, fz = look_at[2] - cz;
    float fn = 1.0f / sqrtf(fx*fx + fy*fy + fz*fz);
    fx *= fn; fy *= fn; fz *= fn;
    float rx = -fz, ry = 0.0f, rz = fx;                 // cross(fwd,(0,1,0))
    float rn = 1.0f / sqrtf(rx*rx + ry*ry + rz*rz);
    rx *= rn; ry *= rn; rz *= rn;
    float ux = ry*fz - rz*fy, uy = rz*fx - rx*fz, uz = rx*fy - ry*fx;

    float mx = means[3*i+0] - cx, my = means[3*i+1] - cy, mz = means[3*i+2] - cz;
    float m0 =  rx*mx + ry*my + rz*mz;
    float m1 =  ux*mx + uy*my + uz*mz;
    float m2 = -(fx*mx + fy*my + fz*mz);
    float d  = -m2;
    float invz = 1.0f / (-m2 + 1e-8f);
    float m2dx =  (m0 * invz) * IMGF + IMGF * 0.5f;
    float m2dy = -(m1 * invz) * IMGF + IMGF * 0.5f;

    float s0 = expf(log_scales[3*i+0]);
    float s1 = expf(log_scales[3*i+1]);
    float s2 = expf(log_scales[3*i+2]);
    float qw = rotations[4*i+0], qx = rotations[4*i+1],
          qy = rotations[4*i+2], qz = rotations[4*i+3];
    float qn = 1.0f / sqrtf(qw*qw + qx*qx + qy*qy + qz*qz);
    qw *= qn; qx *= qn; qy *= qn; qz *= qn;
    float R00 = 1-2*(qy*qy+qz*qz), R01 = 2*(qx*qy-qw*qz), R02 = 2*(qx*qz+qw*qy);
    float R10 = 2*(qx*qy+qw*qz), R11 = 1-2*(qx*qx+qz*qz), R12 = 2*(qy*qz-qw*qx);
    float R20 = 2*(qx*qz-qw*qy), R21 = 2*(qy*qz+qw*qx), R22 = 1-2*(qx*qx+qy*qy);
    float t0 = s0*s0, t1 = s1*s1, t2 = s2*s2;
    float C00 = R00*R00*t0 + R01*R01*t1 + R02*R02*t2;
    float C01 = R00*R10*t0 + R01*R11*t1 + R02*R12*t2;
    float C02 = R00*R20*t0 + R01*R21*t1 + R02*R22*t2;
    float C11 = R10*R10*t0 + R11*R11*t1 + R12*R12*t2;
    float C12 = R10*R20*t0 + R11*R21*t1 + R12*R22*t2;
    float C22 = R20*R20*t0 + R21*R21*t1 + R22*R22*t2;

    float v0 = C00*rx + C01*ry + C02*rz;
    float v1 = C01*rx + C11*ry + C12*rz;
    float v2 = C02*rx + C12*ry + C22*rz;
    float ca = rx*v0 + ry*v1 + rz*v2;
    float cb = ux*v0 + uy*v1 + uz*v2;
    float w0 = C00*ux + C01*uy + C02*uz;
    float w1 = C01*ux + C11*uy + C12*uz;
    float w2 = C02*ux + C12*uy + C22*uz;
    float cd = ux*w0 + uy*w1 + uz*w2;

    float z2 = fmaxf(d*d, 0.01f);
    float sc = (IMGF * IMGF) / z2;
    float a  = ca*sc + 0.3f;
    float b  = cb*sc;
    float dd = cd*sc + 0.3f;
    float det  = fmaxf(a*dd - b*b, 1e-6f);
    float idet = 1.0f / det;

    bool valid = (d > 0.1f) && (m2dx > -IMGF) && (m2dx < 2.0f*IMGF)
                            && (m2dy > -IMGF) && (m2dy < 2.0f*IMGF);

    float op = 1.0f / (1.0f + expf(-opacity_logit[i]));
    const float L2E = 1.4426950408889634f;
    float A2 = -0.5f * L2E * dd * idet;
    float B2 =          L2E * b  * idet;
    float D2 = -0.5f * L2E * a  * idet;
    float L  = valid ? log2f(op) : -1e10f;

    float cr = 1.0f / (1.0f + expf(-color_pre[3*i+0]));
    float cg = 1.0f / (1.0f + expf(-color_pre[3*i+1]));
    float cl = 1.0f / (1.0f + expf(-color_pre[3*i+2]));

    unsigned int hr = __half_as_ushort(__float2half_rn(cr));
    unsigned int hg = __half_as_ushort(__float2half_rn(cg));
    unsigned int hb = __half_as_ushort(__float2half_rn(cl));

    float4* r4 = (float4*)(rec + RECF*i);
    r4[0] = make_float4(m2dx, m2dy, A2, B2);
    r4[1] = make_float4(D2, L,
                        __uint_as_float(hr | (hg << 16)),
                        __uint_as_float(hb));
    depth[i] = d;
}

// O(N^2) stable rank sort, depths staged in LDS. 8 blocks x 256 (4 waves/CU
// overlap the LDS latency). Thread i scatters record to iteration-major slot.
__global__ void __launch_bounds__(256)
gs_rank_scatter(const float* __restrict__ depth,
                const float* __restrict__ rec,
                float* __restrict__ srec)
{
    __shared__ float sd[N_G];
    int t = threadIdx.x;
    int i = blockIdx.x * 256 + t;

    const float4* d4 = (const float4*)depth;
    float4* s4 = (float4*)sd;
    s4[t]       = d4[t];
    s4[t + 256] = d4[t + 256];
    __syncthreads();

    float di = sd[i];
    int rank = 0;
    #pragma unroll 8
    for (int j = 0; j < N_G; j += 4) {
        float4 dj = *(const float4*)(sd + j);
        rank += (dj.x < di) || (dj.x == di && (j+0) < i);
        rank += (dj.y < di) || (dj.y == di && (j+1) < i);
        rank += (dj.z < di) || (dj.z == di && (j+2) < i);
        rank += (dj.w < di) || (dj.w == di && (j+3) < i);
    }
    int slot = (rank & 31) * 64 + (rank >> 5);
    const float4* s = (const float4*)(rec + RECF*i);
    float4*       o = (float4*)(srec + RECF*slot);
    o[0] = s[0]; o[1] = s[1];
}

// Scan-form compositing:
//   u_k = T_{k-1} * alpha_k,  T = prefix-prod(1-alpha)
//   I   = PI_k (1-u_k) + SUM_k u_k c_k PI_{j>k} (1-u_j)
// (verified equal to the reference recurrence by algebraic expansion)
// One wave = 2 adjacent pixels (same row); lane l owns ranks [32l, 32l+32).
__global__ void __launch_bounds__(256)
gs_raster(const float* __restrict__ srec, float* __restrict__ out)
{
    int tid  = threadIdx.x;
    int lane = tid & 63;
    int wave = (blockIdx.x << 2) | (tid >> 6);    // 0..8191
    int p0   = wave * 2;                          // two pixels, same row
    float px0 = (float)(p0 & 127);
    float px1 = px0 + 1.0f;
    float py  = (float)(p0 >> 7);

    float v0[32], v1[32];
    float P0 = 1.0f, P1 = 1.0f;

    // ---- pass 1: alphas + lane-local prefix products ----
    #pragma unroll
    for (int i = 0; i < 32; ++i) {
        const float* r = srec + (size_t)((i << 6) | lane) * RECF;
        float4 ra = *(const float4*)r;            // mux,muy,A2,B2
        float2 rb = *(const float2*)(r + 4);      // D2,L
        float dy   = py - ra.y;
        float b2dy = ra.w * dy;
        float t2   = fmaf(rb.x * dy, dy, rb.y);
        float dx0  = px0 - ra.x;
        float dx1  = px1 - ra.x;
        float q0 = fmaf(dx0, fmaf(ra.z, dx0, b2dy), t2);
        float q1 = fmaf(dx1, fmaf(ra.z, dx1, b2dy), t2);
        float a0 = fminf(__builtin_amdgcn_exp2f(q0), 0.99f);
        float a1 = fminf(__builtin_amdgcn_exp2f(q1), 0.99f);
        v0[i] = P0 * a0;  P0 *= (1.0f - a0);
        v1[i] = P1 * a1;  P1 *= (1.0f - a1);
    }

    // ---- wave exclusive prefix product of lane totals -> T_in per lane ----
    float sp0 = P0, sp1 = P1;
    #pragma unroll
    for (int d = 1; d < 64; d <<= 1) {
        float y0 = __shfl_up(sp0, d);
        float y1 = __shfl_up(sp1, d);
        if (lane >= d) { sp0 *= y0; sp1 *= y1; }
    }
    float e0 = __shfl_up(sp0, 1);
    float e1 = __shfl_up(sp1, 1);
    float Tin0 = (lane == 0) ? 1.0f : e0;
    float Tin1 = (lane == 0) ? 1.0f : e1;

    // ---- pass 2a: lane-local product of (1-u) ----
    float B0 = 1.0f, B1 = 1.0f;
    #pragma unroll
    for (int i = 0; i < 32; ++i) {
        B0 *= fmaf(-Tin0, v0[i], 1.0f);
        B1 *= fmaf(-Tin1, v1[i], 1.0f);
    }

    // ---- wave exclusive suffix product -> S_out per lane ----
    float ss0 = B0, ss1 = B1;
    #pragma unroll
    for (int d = 1; d < 64; d <<= 1) {
        float y0 = __shfl_down(ss0, d);
        float y1 = __shfl_down(ss1, d);
        if (lane + d < 64) { ss0 *= y0; ss1 *= y1; }
    }
    float f0 = __shfl_down(ss0, 1);
    float f1 = __shfl_down(ss1, 1);
    float S0 = (lane == 63) ? 1.0f : f0;
    float S1 = (lane == 63) ? 1.0f : f1;

    // ---- pass 2b: descending accumulate  SUM u*c*S ----
    float ar0 = 0.0f, ag0 = 0.0f, ab0 = 0.0f;
    float ar1 = 0.0f, ag1 = 0.0f, ab1 = 0.0f;
    #pragma unroll
    for (int i = 31; i >= 0; --i) {
        const float* r = srec + (size_t)((i << 6) | lane) * RECF;
        float2 cp = *(const float2*)(r + 6);
        unsigned int w6 = __float_as_uint(cp.x);
        unsigned int w7 = __float_as_uint(cp.y);
        float cr = __half2float(__ushort_as_half((unsigned short)(w6 & 0xFFFFu)));
        float cg = __half2float(__ushort_as_half((unsigned short)(w6 >> 16)));
        float cb = __half2float(__ushort_as_half((unsigned short)(w7 & 0xFFFFu)));
        float u0  = Tin0 * v0[i];
        float us0 = u0 * S0;
        ar0 = fmaf(us0, cr, ar0); ag0 = fmaf(us0, cg, ag0); ab0 = fmaf(us0, cb, ab0);
        S0 *= (1.0f - u0);
        float u1  = Tin1 * v1[i];
        float us1 = u1 * S1;
        ar1 = fmaf(us1, cr, ar1); ag1 = fmaf(us1, cg, ag1); ab1 = fmaf(us1, cb, ab1);
        S1 *= (1.0f - u1);
    }
    // lane 0's S is now the GLOBAL product PI(1-u) = background coefficient

    // ---- wave sum-reduce the accumulators ----
    #pragma unroll
    for (int d = 1; d < 64; d <<= 1) {
        ar0 += __shfl_xor(ar0, d); ag0 += __shfl_xor(ag0, d); ab0 += __shfl_xor(ab0, d);
        ar1 += __shfl_xor(ar1, d); ag1 += __shfl_xor(ag1, d); ab1 += __shfl_xor(ab1, d);
    }

    if (lane == 0) {
        float* o0 = out + (size_t)p0 * 3;
        o0[0] = fminf(fmaxf(S0 + ar0, 0.0f), 1.0f);
        o0[1] = fminf(fmaxf(S0 + ag0, 0.0f), 1.0f);
        o0[2] = fminf(fmaxf(S0 + ab0, 0.0f), 1.0f);
        o0[3] = fminf(fmaxf(S1 + ar1, 0.0f), 1.0f);
        o0[4] = fminf(fmaxf(S1 + ag1, 0.0f), 1.0f);
        o0[5] = fminf(fmaxf(S1 + ab1, 0.0f), 1.0f);
    }
}

extern "C" void kernel_launch(void* const* d_in, const int* in_sizes, int n_in,
                              void* d_out, int out_size, void* d_ws, size_t ws_size,
                              hipStream_t stream)
{
    const float* means         = (const float*)d_in[0];
    const float* log_scales    = (const float*)d_in[1];
    const float* rotations     = (const float*)d_in[2];
    const float* opacity_logit = (const float*)d_in[3];
    const float* color_pre     = (const float*)d_in[4];
    const float* cam_pos       = (const float*)d_in[5];
    const float* look_at       = (const float*)d_in[6];
    float* out = (float*)d_out;

    char* ws = (char*)d_ws;
    float* rec   = (float*)(ws);                                     // 2048*8 f
    float* depth = (float*)(ws + N_G * RECF * 4);                    // 2048 f
    float* srec  = (float*)(ws + N_G * RECF * 4 + N_G * 4);          // 2048*8 f

    hipLaunchKernelGGL(gs_preprocess, dim3(N_G / 256), dim3(256), 0, stream,
                       means, log_scales, rotations, opacity_logit, color_pre,
                       cam_pos, look_at, rec, depth);
    hipLaunchKernelGGL(gs_rank_scatter, dim3(N_G / 256), dim3(256), 0, stream,
                       depth, rec, srec);
    // 16384 px / 2 px-per-wave = 8192 waves; 4 waves/block -> 2048 blocks
    hipLaunchKernelGGL(gs_raster, dim3(2048), dim3(256), 0, stream,
                       srec, out);
}

// Round 7
// 127.457 us; speedup vs baseline: 2.2340x; 1.2582x over previous
//
#include <hip/hip_runtime.h>
#include <hip/hip_bf16.h>
#include <hip/hip_fp16.h>

#define N_G   2048
#define IMGF  128.0f
#define RECF  8          // floats per gaussian record (2 x float4, 32 B)

// record layout (8 floats):
//  [0]=mu_x [1]=mu_y [2]=A2 [3]=B2 [4]=D2 [5]=L [6]=f16pack(cr,cg) [7]=f16pack(cb,0)
// p2 = A2*dx^2 + B2*dx*dy + D2*dy^2 + L ; alpha = min(exp2(p2), 0.99)
// L = log2(opacity) or -1e10 if invalid (exp2 -> 0 reproduces valid-mask)
//
// Sorted storage is ITERATION-MAJOR: rank r lives at slot (r&31)*64 + (r>>5),
// so at inner step i the wave's 64 lanes read 64 adjacent records (coalesced)
// while lane l owns the contiguous rank range [32l, 32l+32) (scan order).
//
// Sort key: u64 = mono32(depth) << 32 | idx  (mono32 = IEEE-order-preserving
// bit flip). Strict total order == stable argsort by depth; single u64 compare.

__global__ void gs_preprocess(const float* __restrict__ means,
                              const float* __restrict__ log_scales,
                              const float* __restrict__ rotations,
                              const float* __restrict__ opacity_logit,
                              const float* __restrict__ color_pre,
                              const float* __restrict__ cam_pos,
                              const float* __restrict__ look_at,
                              float* __restrict__ rec,
                              unsigned long long* __restrict__ keys)
{
    int i = blockIdx.x * blockDim.x + threadIdx.x;
    if (i >= N_G) return;

    float cx = cam_pos[0], cy = cam_pos[1], cz = cam_pos[2];
    float fx = look_at[0] - cx, fy = look_at[1] - cy, fz = look_at[2] - cz;
    float fn = 1.0f / sqrtf(fx*fx + fy*fy + fz*fz);
    fx *= fn; fy *= fn; fz *= fn;
    float rx = -fz, ry = 0.0f, rz = fx;                 // cross(fwd,(0,1,0))
    float rn = 1.0f / sqrtf(rx*rx + ry*ry + rz*rz);
    rx *= rn; ry *= rn; rz *= rn;
    float ux = ry*fz - rz*fy, uy = rz*fx - rx*fz, uz = rx*fy - ry*fx;

    float mx = means[3*i+0] - cx, my = means[3*i+1] - cy, mz = means[3*i+2] - cz;
    float m0 =  rx*mx + ry*my + rz*mz;
    float m1 =  ux*mx + uy*my + uz*mz;
    float m2 = -(fx*mx + fy*my + fz*mz);
    float d  = -m2;
    float invz = 1.0f / (-m2 + 1e-8f);
    float m2dx =  (m0 * invz) * IMGF + IMGF * 0.5f;
    float m2dy = -(m1 * invz) * IMGF + IMGF * 0.5f;

    float s0 = expf(log_scales[3*i+0]);
    float s1 = expf(log_scales[3*i+1]);
    float s2 = expf(log_scales[3*i+2]);
    float qw = rotations[4*i+0], qx = rotations[4*i+1],
          qy = rotations[4*i+2], qz = rotations[4*i+3];
    float qn = 1.0f / sqrtf(qw*qw + qx*qx + qy*qy + qz*qz);
    qw *= qn; qx *= qn; qy *= qn; qz *= qn;
    float R00 = 1-2*(qy*qy+qz*qz), R01 = 2*(qx*qy-qw*qz), R02 = 2*(qx*qz+qw*qy);
    float R10 = 2*(qx*qy+qw*qz), R11 = 1-2*(qx*qx+qz*qz), R12 = 2*(qy*qz-qw*qx);
    float R20 = 2*(qx*qz-qw*qy), R21 = 2*(qy*qz+qw*qx), R22 = 1-2*(qx*qx+qy*qy);
    float t0 = s0*s0, t1 = s1*s1, t2 = s2*s2;
    float C00 = R00*R00*t0 + R01*R01*t1 + R02*R02*t2;
    float C01 = R00*R10*t0 + R01*R11*t1 + R02*R12*t2;
    float C02 = R00*R20*t0 + R01*R21*t1 + R02*R22*t2;
    float C11 = R10*R10*t0 + R11*R11*t1 + R12*R12*t2;
    float C12 = R10*R20*t0 + R11*R21*t1 + R12*R22*t2;
    float C22 = R20*R20*t0 + R21*R21*t1 + R22*R22*t2;

    float v0 = C00*rx + C01*ry + C02*rz;
    float v1 = C01*rx + C11*ry + C12*rz;
    float v2 = C02*rx + C12*ry + C22*rz;
    float ca = rx*v0 + ry*v1 + rz*v2;
    float cb = ux*v0 + uy*v1 + uz*v2;
    float w0 = C00*ux + C01*uy + C02*uz;
    float w1 = C01*ux + C11*uy + C12*uz;
    float w2 = C02*ux + C12*uy + C22*uz;
    float cd = ux*w0 + uy*w1 + uz*w2;

    float z2 = fmaxf(d*d, 0.01f);
    float sc = (IMGF * IMGF) / z2;
    float a  = ca*sc + 0.3f;
    float b  = cb*sc;
    float dd = cd*sc + 0.3f;
    float det  = fmaxf(a*dd - b*b, 1e-6f);
    float idet = 1.0f / det;

    bool valid = (d > 0.1f) && (m2dx > -IMGF) && (m2dx < 2.0f*IMGF)
                            && (m2dy > -IMGF) && (m2dy < 2.0f*IMGF);

    float op = 1.0f / (1.0f + expf(-opacity_logit[i]));
    const float L2E = 1.4426950408889634f;
    float A2 = -0.5f * L2E * dd * idet;
    float B2 =          L2E * b  * idet;
    float D2 = -0.5f * L2E * a  * idet;
    float L  = valid ? log2f(op) : -1e10f;

    float cr = 1.0f / (1.0f + expf(-color_pre[3*i+0]));
    float cg = 1.0f / (1.0f + expf(-color_pre[3*i+1]));
    float cl = 1.0f / (1.0f + expf(-color_pre[3*i+2]));

    unsigned int hr = __half_as_ushort(__float2half_rn(cr));
    unsigned int hg = __half_as_ushort(__float2half_rn(cg));
    unsigned int hb = __half_as_ushort(__float2half_rn(cl));

    float4* r4 = (float4*)(rec + RECF*i);
    r4[0] = make_float4(m2dx, m2dy, A2, B2);
    r4[1] = make_float4(D2, L,
                        __uint_as_float(hr | (hg << 16)),
                        __uint_as_float(hb));

    unsigned int ub   = __float_as_uint(d);
    unsigned int mask = ((unsigned int)((int)ub >> 31)) | 0x80000000u;
    keys[i] = ((unsigned long long)(ub ^ mask) << 32) | (unsigned int)i;
}

// O(N^2) stable rank sort on u64 keys staged in LDS. 8 blocks x 256.
// launch_bounds(...,1): allow high VGPR so the 16B LDS loads stay in flight.
__global__ void __launch_bounds__(256, 1)
gs_rank_scatter(const unsigned long long* __restrict__ keys,
                const float* __restrict__ rec,
                float* __restrict__ srec)
{
    __shared__ __align__(16) unsigned long long sk[N_G];
    int t = threadIdx.x;
    int i = blockIdx.x * 256 + t;

    const ulonglong2* k2 = (const ulonglong2*)keys;
    ulonglong2* s2 = (ulonglong2*)sk;
    #pragma unroll
    for (int q = 0; q < 4; ++q) s2[t + q*256] = k2[t + q*256];   // 16 KB
    __syncthreads();

    unsigned long long ki = sk[i];
    int rank = 0;
    #pragma unroll 4
    for (int j = 0; j < N_G; j += 8) {
        ulonglong2 a = *(const ulonglong2*)(sk + j);
        ulonglong2 b = *(const ulonglong2*)(sk + j + 2);
        ulonglong2 c = *(const ulonglong2*)(sk + j + 4);
        ulonglong2 d = *(const ulonglong2*)(sk + j + 6);
        rank += (int)(a.x < ki) + (int)(a.y < ki)
              + (int)(b.x < ki) + (int)(b.y < ki)
              + (int)(c.x < ki) + (int)(c.y < ki)
              + (int)(d.x < ki) + (int)(d.y < ki);
    }
    int slot = (rank & 31) * 64 + (rank >> 5);
    const float4* s = (const float4*)(rec + RECF*i);
    float4*       o = (float4*)(srec + RECF*slot);
    o[0] = s[0]; o[1] = s[1];
}

// Scan-form compositing:
//   u_k = T_{k-1} * alpha_k,  T = prefix-prod(1-alpha)
//   I   = PI_k (1-u_k) + SUM_k u_k c_k PI_{j>k} (1-u_j)
// One wave = 2 adjacent pixels (same row); lane l owns ranks [32l, 32l+32).
__global__ void __launch_bounds__(256)
gs_raster(const float* __restrict__ srec, float* __restrict__ out)
{
    int tid  = threadIdx.x;
    int lane = tid & 63;
    int wave = (blockIdx.x << 2) | (tid >> 6);    // 0..8191
    int p0   = wave * 2;                          // two pixels, same row
    float px0 = (float)(p0 & 127);
    float px1 = px0 + 1.0f;
    float py  = (float)(p0 >> 7);

    float v0[32], v1[32];
    float P0 = 1.0f, P1 = 1.0f;

    // ---- pass 1: alphas + lane-local prefix products ----
    #pragma unroll
    for (int i = 0; i < 32; ++i) {
        const float* r = srec + (size_t)((i << 6) | lane) * RECF;
        float4 ra = *(const float4*)r;            // mux,muy,A2,B2
        float2 rb = *(const float2*)(r + 4);      // D2,L
        float dy   = py - ra.y;
        float b2dy = ra.w * dy;
        float t2   = fmaf(rb.x * dy, dy, rb.y);
        float dx0  = px0 - ra.x;
        float dx1  = px1 - ra.x;
        float q0 = fmaf(dx0, fmaf(ra.z, dx0, b2dy), t2);
        float q1 = fmaf(dx1, fmaf(ra.z, dx1, b2dy), t2);
        float a0 = fminf(__builtin_amdgcn_exp2f(q0), 0.99f);
        float a1 = fminf(__builtin_amdgcn_exp2f(q1), 0.99f);
        v0[i] = P0 * a0;  P0 *= (1.0f - a0);
        v1[i] = P1 * a1;  P1 *= (1.0f - a1);
    }

    // ---- wave exclusive prefix product of lane totals -> T_in per lane ----
    float sp0 = P0, sp1 = P1;
    #pragma unroll
    for (int d = 1; d < 64; d <<= 1) {
        float y0 = __shfl_up(sp0, d);
        float y1 = __shfl_up(sp1, d);
        if (lane >= d) { sp0 *= y0; sp1 *= y1; }
    }
    float e0 = __shfl_up(sp0, 1);
    float e1 = __shfl_up(sp1, 1);
    float Tin0 = (lane == 0) ? 1.0f : e0;
    float Tin1 = (lane == 0) ? 1.0f : e1;

    // ---- pass 2a: lane-local product of (1-u) ----
    float B0 = 1.0f, B1 = 1.0f;
    #pragma unroll
    for (int i = 0; i < 32; ++i) {
        B0 *= fmaf(-Tin0, v0[i], 1.0f);
        B1 *= fmaf(-Tin1, v1[i], 1.0f);
    }

    // ---- wave exclusive suffix product -> S_out per lane ----
    float ss0 = B0, ss1 = B1;
    #pragma unroll
    for (int d = 1; d < 64; d <<= 1) {
        float y0 = __shfl_down(ss0, d);
        float y1 = __shfl_down(ss1, d);
        if (lane + d < 64) { ss0 *= y0; ss1 *= y1; }
    }
    float f0 = __shfl_down(ss0, 1);
    float f1 = __shfl_down(ss1, 1);
    float S0 = (lane == 63) ? 1.0f : f0;
    float S1 = (lane == 63) ? 1.0f : f1;

    // ---- pass 2b: descending accumulate  SUM u*c*S ----
    float ar0 = 0.0f, ag0 = 0.0f, ab0 = 0.0f;
    float ar1 = 0.0f, ag1 = 0.0f, ab1 = 0.0f;
    #pragma unroll
    for (int i = 31; i >= 0; --i) {
        const float* r = srec + (size_t)((i << 6) | lane) * RECF;
        float2 cp = *(const float2*)(r + 6);
        unsigned int w6 = __float_as_uint(cp.x);
        unsigned int w7 = __float_as_uint(cp.y);
        float cr = __half2float(__ushort_as_half((unsigned short)(w6 & 0xFFFFu)));
        float cg = __half2float(__ushort_as_half((unsigned short)(w6 >> 16)));
        float cb = __half2float(__ushort_as_half((unsigned short)(w7 & 0xFFFFu)));
        float u0  = Tin0 * v0[i];
        float us0 = u0 * S0;
        ar0 = fmaf(us0, cr, ar0); ag0 = fmaf(us0, cg, ag0); ab0 = fmaf(us0, cb, ab0);
        S0 *= (1.0f - u0);
        float u1  = Tin1 * v1[i];
        float us1 = u1 * S1;
        ar1 = fmaf(us1, cr, ar1); ag1 = fmaf(us1, cg, ag1); ab1 = fmaf(us1, cb, ab1);
        S1 *= (1.0f - u1);
    }
    // lane 0's S is now the GLOBAL product PI(1-u) = background coefficient

    // ---- wave sum-reduce the accumulators ----
    #pragma unroll
    for (int d = 1; d < 64; d <<= 1) {
        ar0 += __shfl_xor(ar0, d); ag0 += __shfl_xor(ag0, d); ab0 += __shfl_xor(ab0, d);
        ar1 += __shfl_xor(ar1, d); ag1 += __shfl_xor(ag1, d); ab1 += __shfl_xor(ab1, d);
    }

    if (lane == 0) {
        float* o0 = out + (size_t)p0 * 3;
        o0[0] = fminf(fmaxf(S0 + ar0, 0.0f), 1.0f);
        o0[1] = fminf(fmaxf(S0 + ag0, 0.0f), 1.0f);
        o0[2] = fminf(fmaxf(S0 + ab0, 0.0f), 1.0f);
        o0[3] = fminf(fmaxf(S1 + ar1, 0.0f), 1.0f);
        o0[4] = fminf(fmaxf(S1 + ag1, 0.0f), 1.0f);
        o0[5] = fminf(fmaxf(S1 + ab1, 0.0f), 1.0f);
    }
}

extern "C" void kernel_launch(void* const* d_in, const int* in_sizes, int n_in,
                              void* d_out, int out_size, void* d_ws, size_t ws_size,
                              hipStream_t stream)
{
    const float* means         = (const float*)d_in[0];
    const float* log_scales    = (const float*)d_in[1];
    const float* rotations     = (const float*)d_in[2];
    const float* opacity_logit = (const float*)d_in[3];
    const float* color_pre     = (const float*)d_in[4];
    const float* cam_pos       = (const float*)d_in[5];
    const float* look_at       = (const float*)d_in[6];
    float* out = (float*)d_out;

    char* ws = (char*)d_ws;
    float*              rec  = (float*)(ws);                         // 64 KB
    unsigned long long* keys = (unsigned long long*)(ws + 65536);    // 16 KB
    float*              srec = (float*)(ws + 65536 + 16384);         // 64 KB

    hipLaunchKernelGGL(gs_preprocess, dim3(N_G / 256), dim3(256), 0, stream,
                       means, log_scales, rotations, opacity_logit, color_pre,
                       cam_pos, look_at, rec, keys);
    hipLaunchKernelGGL(gs_rank_scatter, dim3(N_G / 256), dim3(256), 0, stream,
                       keys, rec, srec);
    // 16384 px / 2 px-per-wave = 8192 waves; 4 waves/block -> 2048 blocks
    hipLaunchKernelGGL(gs_raster, dim3(2048), dim3(256), 0, stream,
                       srec, out);
}

// Round 9
// 115.883 us; speedup vs baseline: 2.4571x; 1.0999x over previous
//
#include <hip/hip_runtime.h>
#include <hip/hip_bf16.h>
#include <hip/hip_fp16.h>

#define N_G   2048
#define IMGF  128.0f
#define RECF  8          // floats per gaussian record (2 x float4, 32 B)

// record layout (8 floats):
//  [0]=mu_x [1]=mu_y [2]=A2 [3]=B2 [4]=D2 [5]=L
//  [6]=bf16pack(cr|cg<<16) [7]=bf16pack(cb)
// p2 = A2*dx^2 + B2*dx*dy + D2*dy^2 + L ; alpha = min(exp2(p2), 0.99)
// L = log2(opacity) or -1e10 if invalid (exp2 -> 0 reproduces valid-mask)
//
// Sorted storage is ITERATION-MAJOR: rank r lives at slot (r&31)*64 + (r>>5):
// at inner step i the wave's 64 lanes read 64 adjacent records (coalesced)
// while lane l owns the contiguous rank range [32l, 32l+32) (scan order).
//
// Sort key: u64 = mono32(depth) << 32 | idx -> stable argsort, 1 u64 compare.

typedef __fp16 half2_v __attribute__((ext_vector_type(2)));
union H2U { half2_v h2; float f; unsigned int u; };

static __device__ __forceinline__ unsigned int f32_bf16(float f) {
    unsigned int u = __float_as_uint(f);
    return (u + 0x7FFFu + ((u >> 16) & 1u)) >> 16;      // RNE, finite inputs
}

__global__ void gs_preprocess(const float* __restrict__ means,
                              const float* __restrict__ log_scales,
                              const float* __restrict__ rotations,
                              const float* __restrict__ opacity_logit,
                              const float* __restrict__ color_pre,
                              const float* __restrict__ cam_pos,
                              const float* __restrict__ look_at,
                              float* __restrict__ rec,
                              unsigned long long* __restrict__ keys)
{
    int i = blockIdx.x * blockDim.x + threadIdx.x;
    if (i >= N_G) return;

    float cx = cam_pos[0], cy = cam_pos[1], cz = cam_pos[2];
    float fx = look_at[0] - cx, fy = look_at[1] - cy, fz = look_at[2] - cz;
    float fn = 1.0f / sqrtf(fx*fx + fy*fy + fz*fz);
    fx *= fn; fy *= fn; fz *= fn;
    float rx = -fz, ry = 0.0f, rz = fx;                 // cross(fwd,(0,1,0))
    float rn = 1.0f / sqrtf(rx*rx + ry*ry + rz*rz);
    rx *= rn; ry *= rn; rz *= rn;
    float ux = ry*fz - rz*fy, uy = rz*fx - rx*fz, uz = rx*fy - ry*fx;

    float mx = means[3*i+0] - cx, my = means[3*i+1] - cy, mz = means[3*i+2] - cz;
    float m0 =  rx*mx + ry*my + rz*mz;
    float m1 =  ux*mx + uy*my + uz*mz;
    float m2 = -(fx*mx + fy*my + fz*mz);
    float d  = -m2;
    float invz = 1.0f / (-m2 + 1e-8f);
    float m2dx =  (m0 * invz) * IMGF + IMGF * 0.5f;
    float m2dy = -(m1 * invz) * IMGF + IMGF * 0.5f;

    float s0 = expf(log_scales[3*i+0]);
    float s1 = expf(log_scales[3*i+1]);
    float s2 = expf(log_scales[3*i+2]);
    float qw = rotations[4*i+0], qx = rotations[4*i+1],
          qy = rotations[4*i+2], qz = rotations[4*i+3];
    float qn = 1.0f / sqrtf(qw*qw + qx*qx + qy*qy + qz*qz);
    qw *= qn; qx *= qn; qy *= qn; qz *= qn;
    float R00 = 1-2*(qy*qy+qz*qz), R01 = 2*(qx*qy-qw*qz), R02 = 2*(qx*qz+qw*qy);
    float R10 = 2*(qx*qy+qw*qz), R11 = 1-2*(qx*qx+qz*qz), R12 = 2*(qy*qz-qw*qx);
    float R20 = 2*(qx*qz-qw*qy), R21 = 2*(qy*qz+qw*qx), R22 = 1-2*(qx*qx+qy*qy);
    float t0 = s0*s0, t1 = s1*s1, t2 = s2*s2;
    float C00 = R00*R00*t0 + R01*R01*t1 + R02*R02*t2;
    float C01 = R00*R10*t0 + R01*R11*t1 + R02*R12*t2;
    float C02 = R00*R20*t0 + R01*R21*t1 + R02*R22*t2;
    float C11 = R10*R10*t0 + R11*R11*t1 + R12*R12*t2;
    float C12 = R10*R20*t0 + R11*R21*t1 + R12*R22*t2;
    float C22 = R20*R20*t0 + R21*R21*t1 + R22*R22*t2;

    float v0 = C00*rx + C01*ry + C02*rz;
    float v1 = C01*rx + C11*ry + C12*rz;
    float v2 = C02*rx + C12*ry + C22*rz;
    float ca = rx*v0 + ry*v1 + rz*v2;
    float cb = ux*v0 + uy*v1 + uz*v2;
    float w0 = C00*ux + C01*uy + C02*uz;
    float w1 = C01*ux + C11*uy + C12*uz;
    float w2 = C02*ux + C12*uy + C22*uz;
    float cd = ux*w0 + uy*w1 + uz*w2;

    float z2 = fmaxf(d*d, 0.01f);
    float sc = (IMGF * IMGF) / z2;
    float a  = ca*sc + 0.3f;
    float b  = cb*sc;
    float dd = cd*sc + 0.3f;
    float det  = fmaxf(a*dd - b*b, 1e-6f);
    float idet = 1.0f / det;

    bool valid = (d > 0.1f) && (m2dx > -IMGF) && (m2dx < 2.0f*IMGF)
                            && (m2dy > -IMGF) && (m2dy < 2.0f*IMGF);

    float op = 1.0f / (1.0f + expf(-opacity_logit[i]));
    const float L2E = 1.4426950408889634f;
    float A2 = -0.5f * L2E * dd * idet;
    float B2 =          L2E * b  * idet;
    float D2 = -0.5f * L2E * a  * idet;
    float L  = valid ? log2f(op) : -1e10f;

    float cr = 1.0f / (1.0f + expf(-color_pre[3*i+0]));
    float cg = 1.0f / (1.0f + expf(-color_pre[3*i+1]));
    float cl = 1.0f / (1.0f + expf(-color_pre[3*i+2]));

    unsigned int w6 = f32_bf16(cr) | (f32_bf16(cg) << 16);
    unsigned int w7 = f32_bf16(cl);

    float4* r4 = (float4*)(rec + RECF*i);
    r4[0] = make_float4(m2dx, m2dy, A2, B2);
    r4[1] = make_float4(D2, L, __uint_as_float(w6), __uint_as_float(w7));

    unsigned int ub   = __float_as_uint(d);
    unsigned int mask = ((unsigned int)((int)ub >> 31)) | 0x80000000u;
    keys[i] = ((unsigned long long)(ub ^ mask) << 32) | (unsigned int)i;
}

// O(N^2) stable rank sort: 64 blocks x 256; 8 threads per gaussian, each
// counting a 256-key segment (seg-skewed LDS reads -> conflict-free), then
// 3-step shfl combine; 8 threads cooperatively copy the 32B record.
__global__ void __launch_bounds__(256)
gs_rank_scatter(const unsigned long long* __restrict__ keys,
                const float* __restrict__ rec,
                float* __restrict__ srec)
{
    __shared__ __align__(16) unsigned long long sk[N_G];
    int t = threadIdx.x;

    const ulonglong2* k2 = (const ulonglong2*)keys;
    ulonglong2* s2 = (ulonglong2*)sk;
    #pragma unroll
    for (int q = 0; q < 4; ++q) s2[t + q*256] = k2[t + q*256];   // 16 KB
    __syncthreads();

    int g   = (blockIdx.x << 5) | (t >> 3);       // 32 gaussians per block
    int seg = t & 7;                              // 8 segments x 256 keys
    unsigned long long ki = sk[g];
    const ulonglong2* sseg = (const ulonglong2*)(sk + (seg << 8));
    int rank = 0;
    #pragma unroll 8
    for (int j = 0; j < 128; ++j) {
        ulonglong2 a = sseg[(j + seg * 17) & 127];   // skew: distinct banks
        rank += (int)(a.x < ki) + (int)(a.y < ki);
    }
    rank += __shfl_xor(rank, 1);
    rank += __shfl_xor(rank, 2);
    rank += __shfl_xor(rank, 4);

    int slot = ((rank & 31) << 6) | (rank >> 5);
    srec[slot * RECF + seg] = rec[g * RECF + seg];
}

// Scan-form compositing:
//   u_k = T_{k-1} * alpha_k,  T = prefix-prod(1-alpha)
//   I   = PI_k (1-u_k) + SUM_k u_k c_k PI_{j>k} (1-u_j)
// One wave = 2 adjacent pixels; lane l owns ranks [32l, 32l+32).
// v-array packed as f16 pairs (32 VGPRs instead of 64) for occupancy.
__global__ void __launch_bounds__(256, 4)
gs_raster(const float* __restrict__ srec, float* __restrict__ out)
{
    int tid  = threadIdx.x;
    int lane = tid & 63;
    int wave = (blockIdx.x << 2) | (tid >> 6);    // 0..8191
    int p0   = wave * 2;                          // two pixels, same row
    float px0 = (float)(p0 & 127);
    float px1 = px0 + 1.0f;
    float py  = (float)(p0 >> 7);

    float vp[32];                                 // f16x2-packed (u0,u1)
    float P0 = 1.0f, P1 = 1.0f;

    // ---- pass 1: alphas + lane-local prefix products ----
    #pragma unroll
    for (int i = 0; i < 32; ++i) {
        const float* r = srec + (size_t)((i << 6) | lane) * RECF;
        float4 ra = *(const float4*)r;            // mux,muy,A2,B2
        float2 rb = *(const float2*)(r + 4);      // D2,L
        float dy   = py - ra.y;
        float b2dy = ra.w * dy;
        float t2   = fmaf(rb.x * dy, dy, rb.y);
        float dx0  = px0 - ra.x;
        float dx1  = px1 - ra.x;
        float q0 = fmaf(dx0, fmaf(ra.z, dx0, b2dy), t2);
        float q1 = fmaf(dx1, fmaf(ra.z, dx1, b2dy), t2);
        float a0 = fminf(__builtin_amdgcn_exp2f(q0), 0.99f);
        float a1 = fminf(__builtin_amdgcn_exp2f(q1), 0.99f);
        float u0 = P0 * a0;  P0 *= (1.0f - a0);
        float u1 = P1 * a1;  P1 *= (1.0f - a1);
        H2U hp; hp.h2 = __builtin_amdgcn_cvt_pkrtz(u0, u1);
        vp[i] = hp.f;
    }

    // ---- wave exclusive prefix product of lane totals -> T_in per lane ----
    float sp0 = P0, sp1 = P1;
    #pragma unroll
    for (int d = 1; d < 64; d <<= 1) {
        float y0 = __shfl_up(sp0, d);
        float y1 = __shfl_up(sp1, d);
        if (lane >= d) { sp0 *= y0; sp1 *= y1; }
    }
    float e0 = __shfl_up(sp0, 1);
    float e1 = __shfl_up(sp1, 1);
    float Tin0 = (lane == 0) ? 1.0f : e0;
    float Tin1 = (lane == 0) ? 1.0f : e1;

    // ---- pass 2a: lane-local product of (1-u) ----
    float B0 = 1.0f, B1 = 1.0f;
    #pragma unroll
    for (int i = 0; i < 32; ++i) {
        H2U h; h.f = vp[i];
        B0 *= fmaf(-Tin0, (float)h.h2.x, 1.0f);
        B1 *= fmaf(-Tin1, (float)h.h2.y, 1.0f);
    }

    // ---- wave exclusive suffix product -> S_out per lane ----
    float ss0 = B0, ss1 = B1;
    #pragma unroll
    for (int d = 1; d < 64; d <<= 1) {
        float y0 = __shfl_down(ss0, d);
        float y1 = __shfl_down(ss1, d);
        if (lane + d < 64) { ss0 *= y0; ss1 *= y1; }
    }
    float f0 = __shfl_down(ss0, 1);
    float f1 = __shfl_down(ss1, 1);
    float S0 = (lane == 63) ? 1.0f : f0;
    float S1 = (lane == 63) ? 1.0f : f1;

    // ---- pass 2b: descending accumulate  SUM u*c*S ----
    float ar0 = 0.0f, ag0 = 0.0f, ab0 = 0.0f;
    float ar1 = 0.0f, ag1 = 0.0f, ab1 = 0.0f;
    #pragma unroll
    for (int i = 31; i >= 0; --i) {
        const float* r = srec + (size_t)((i << 6) | lane) * RECF;
        float2 cp = *(const float2*)(r + 6);
        unsigned int w6 = __float_as_uint(cp.x);
        unsigned int w7 = __float_as_uint(cp.y);
        float cr = __uint_as_float(w6 << 16);          // bf16 -> f32: 1 shl
        float cg = __uint_as_float(w6 & 0xFFFF0000u);
        float cb = __uint_as_float(w7 << 16);
        H2U h; h.f = vp[i];
        float u0  = Tin0 * (float)h.h2.x;
        float us0 = u0 * S0;
        ar0 = fmaf(us0, cr, ar0); ag0 = fmaf(us0, cg, ag0); ab0 = fmaf(us0, cb, ab0);
        S0 = fmaf(-u0, S0, S0);
        float u1  = Tin1 * (float)h.h2.y;
        float us1 = u1 * S1;
        ar1 = fmaf(us1, cr, ar1); ag1 = fmaf(us1, cg, ag1); ab1 = fmaf(us1, cb, ab1);
        S1 = fmaf(-u1, S1, S1);
    }
    // lane 0's S is now the GLOBAL product PI(1-u) = background coefficient

    // ---- wave sum-reduce the accumulators ----
    #pragma unroll
    for (int d = 1; d < 64; d <<= 1) {
        ar0 += __shfl_xor(ar0, d); ag0 += __shfl_xor(ag0, d); ab0 += __shfl_xor(ab0, d);
        ar1 += __shfl_xor(ar1, d); ag1 += __shfl_xor(ag1, d); ab1 += __shfl_xor(ab1, d);
    }

    if (lane == 0) {
        float* o0 = out + (size_t)p0 * 3;
        o0[0] = fminf(fmaxf(S0 + ar0, 0.0f), 1.0f);
        o0[1] = fminf(fmaxf(S0 + ag0, 0.0f), 1.0f);
        o0[2] = fminf(fmaxf(S0 + ab0, 0.0f), 1.0f);
        o0[3] = fminf(fmaxf(S1 + ar1, 0.0f), 1.0f);
        o0[4] = fminf(fmaxf(S1 + ag1, 0.0f), 1.0f);
        o0[5] = fminf(fmaxf(S1 + ab1, 0.0f), 1.0f);
    }
}

extern "C" void kernel_launch(void* const* d_in, const int* in_sizes, int n_in,
                              void* d_out, int out_size, void* d_ws, size_t ws_size,
                              hipStream_t stream)
{
    const float* means         = (const float*)d_in[0];
    const float* log_scales    = (const float*)d_in[1];
    const float* rotations     = (const float*)d_in[2];
    const float* opacity_logit = (const float*)d_in[3];
    const float* color_pre     = (const float*)d_in[4];
    const float* cam_pos       = (const float*)d_in[5];
    const float* look_at       = (const float*)d_in[6];
    float* out = (float*)d_out;

    char* ws = (char*)d_ws;
    float*              rec  = (float*)(ws);                         // 64 KB
    unsigned long long* keys = (unsigned long long*)(ws + 65536);    // 16 KB
    float*              srec = (float*)(ws + 65536 + 16384);         // 64 KB

    hipLaunchKernelGGL(gs_preprocess, dim3(N_G / 256), dim3(256), 0, stream,
                       means, log_scales, rotations, opacity_logit, color_pre,
                       cam_pos, look_at, rec, keys);
    hipLaunchKernelGGL(gs_rank_scatter, dim3(N_G / 32), dim3(256), 0, stream,
                       keys, rec, srec);
    // 16384 px / 2 px-per-wave = 8192 waves; 4 waves/block -> 2048 blocks
    hipLaunchKernelGGL(gs_raster, dim3(2048), dim3(256), 0, stream,
                       srec, out);
}

// Round 10
// 106.289 us; speedup vs baseline: 2.6789x; 1.0903x over previous
//
#include <hip/hip_runtime.h>
#include <hip/hip_bf16.h>
#include <hip/hip_fp16.h>

#define N_G   2048
#define IMGF  128.0f
#define RECF  8          // floats per gaussian record (2 x float4, 32 B)

// record layout (8 floats):
//  [0]=mu_x [1]=mu_y [2]=A2 [3]=B2 [4]=D2 [5]=L
//  [6]=bf16pack(cr|cg<<16) [7]=bf16pack(cb)
// p2 = A2*dx^2 + B2*dx*dy + D2*dy^2 + L ; alpha = min(exp2(p2), 0.99)
// L = log2(opacity) or -1e10 if invalid (exp2 -> 0 reproduces valid-mask)
//
// Sorted storage is ITERATION-MAJOR: rank r lives at slot (r&31)*64 + (r>>5):
// at inner step i the wave's 64 lanes read 64 adjacent records (coalesced)
// while lane l owns the contiguous rank range [32l, 32l+32) (scan order).
//
// Sort key: u64 = mono32(depth) << 32 | idx -> stable argsort, 1 u64 compare.

typedef __fp16 half2_v __attribute__((ext_vector_type(2)));
union H2U { half2_v h2; float f; unsigned int u; };

static __device__ __forceinline__ unsigned int f32_bf16(float f) {
    unsigned int u = __float_as_uint(f);
    return (u + 0x7FFFu + ((u >> 16) & 1u)) >> 16;      // RNE, finite inputs
}

__global__ void gs_preprocess(const float* __restrict__ means,
                              const float* __restrict__ log_scales,
                              const float* __restrict__ rotations,
                              const float* __restrict__ opacity_logit,
                              const float* __restrict__ color_pre,
                              const float* __restrict__ cam_pos,
                              const float* __restrict__ look_at,
                              float* __restrict__ rec,
                              unsigned long long* __restrict__ keys)
{
    int i = blockIdx.x * blockDim.x + threadIdx.x;
    if (i >= N_G) return;

    float cx = cam_pos[0], cy = cam_pos[1], cz = cam_pos[2];
    float fx = look_at[0] - cx, fy = look_at[1] - cy, fz = look_at[2] - cz;
    float fn = 1.0f / sqrtf(fx*fx + fy*fy + fz*fz);
    fx *= fn; fy *= fn; fz *= fn;
    float rx = -fz, ry = 0.0f, rz = fx;                 // cross(fwd,(0,1,0))
    float rn = 1.0f / sqrtf(rx*rx + ry*ry + rz*rz);
    rx *= rn; ry *= rn; rz *= rn;
    float ux = ry*fz - rz*fy, uy = rz*fx - rx*fz, uz = rx*fy - ry*fx;

    float mx = means[3*i+0] - cx, my = means[3*i+1] - cy, mz = means[3*i+2] - cz;
    float m0 =  rx*mx + ry*my + rz*mz;
    float m1 =  ux*mx + uy*my + uz*mz;
    float m2 = -(fx*mx + fy*my + fz*mz);
    float d  = -m2;
    float invz = 1.0f / (-m2 + 1e-8f);
    float m2dx =  (m0 * invz) * IMGF + IMGF * 0.5f;
    float m2dy = -(m1 * invz) * IMGF + IMGF * 0.5f;

    float s0 = expf(log_scales[3*i+0]);
    float s1 = expf(log_scales[3*i+1]);
    float s2 = expf(log_scales[3*i+2]);
    float qw = rotations[4*i+0], qx = rotations[4*i+1],
          qy = rotations[4*i+2], qz = rotations[4*i+3];
    float qn = 1.0f / sqrtf(qw*qw + qx*qx + qy*qy + qz*qz);
    qw *= qn; qx *= qn; qy *= qn; qz *= qn;
    float R00 = 1-2*(qy*qy+qz*qz), R01 = 2*(qx*qy-qw*qz), R02 = 2*(qx*qz+qw*qy);
    float R10 = 2*(qx*qy+qw*qz), R11 = 1-2*(qx*qx+qz*qz), R12 = 2*(qy*qz-qw*qx);
    float R20 = 2*(qx*qz-qw*qy), R21 = 2*(qy*qz+qw*qx), R22 = 1-2*(qx*qx+qy*qy);
    float t0 = s0*s0, t1 = s1*s1, t2 = s2*s2;
    float C00 = R00*R00*t0 + R01*R01*t1 + R02*R02*t2;
    float C01 = R00*R10*t0 + R01*R11*t1 + R02*R12*t2;
    float C02 = R00*R20*t0 + R01*R21*t1 + R02*R22*t2;
    float C11 = R10*R10*t0 + R11*R11*t1 + R12*R12*t2;
    float C12 = R10*R20*t0 + R11*R21*t1 + R12*R22*t2;
    float C22 = R20*R20*t0 + R21*R21*t1 + R22*R22*t2;

    float v0 = C00*rx + C01*ry + C02*rz;
    float v1 = C01*rx + C11*ry + C12*rz;
    float v2 = C02*rx + C12*ry + C22*rz;
    float ca = rx*v0 + ry*v1 + rz*v2;
    float cb = ux*v0 + uy*v1 + uz*v2;
    float w0 = C00*ux + C01*uy + C02*uz;
    float w1 = C01*ux + C11*uy + C12*uz;
    float w2 = C02*ux + C12*uy + C22*uz;
    float cd = ux*w0 + uy*w1 + uz*w2;

    float z2 = fmaxf(d*d, 0.01f);
    float sc = (IMGF * IMGF) / z2;
    float a  = ca*sc + 0.3f;
    float b  = cb*sc;
    float dd = cd*sc + 0.3f;
    float det  = fmaxf(a*dd - b*b, 1e-6f);
    float idet = 1.0f / det;

    bool valid = (d > 0.1f) && (m2dx > -IMGF) && (m2dx < 2.0f*IMGF)
                            && (m2dy > -IMGF) && (m2dy < 2.0f*IMGF);

    float op = 1.0f / (1.0f + expf(-opacity_logit[i]));
    const float L2E = 1.4426950408889634f;
    float A2 = -0.5f * L2E * dd * idet;
    float B2 =          L2E * b  * idet;
    float D2 = -0.5f * L2E * a  * idet;
    float L  = valid ? log2f(op) : -1e10f;

    float cr = 1.0f / (1.0f + expf(-color_pre[3*i+0]));
    float cg = 1.0f / (1.0f + expf(-color_pre[3*i+1]));
    float cl = 1.0f / (1.0f + expf(-color_pre[3*i+2]));

    unsigned int w6 = f32_bf16(cr) | (f32_bf16(cg) << 16);
    unsigned int w7 = f32_bf16(cl);

    float4* r4 = (float4*)(rec + RECF*i);
    r4[0] = make_float4(m2dx, m2dy, A2, B2);
    r4[1] = make_float4(D2, L, __uint_as_float(w6), __uint_as_float(w7));

    unsigned int ub   = __float_as_uint(d);
    unsigned int mask = ((unsigned int)((int)ub >> 31)) | 0x80000000u;
    keys[i] = ((unsigned long long)(ub ^ mask) << 32) | (unsigned int)i;
}

// O(N^2) stable rank sort: 64 blocks x 256; 8 threads per gaussian, each
// counting a 256-key segment (seg-skewed LDS reads -> conflict-free), then
// 3-step shfl combine; 8 threads cooperatively copy the 32B record.
__global__ void __launch_bounds__(256)
gs_rank_scatter(const unsigned long long* __restrict__ keys,
                const float* __restrict__ rec,
                float* __restrict__ srec)
{
    __shared__ __align__(16) unsigned long long sk[N_G];
    int t = threadIdx.x;

    const ulonglong2* k2 = (const ulonglong2*)keys;
    ulonglong2* s2 = (ulonglong2*)sk;
    #pragma unroll
    for (int q = 0; q < 4; ++q) s2[t + q*256] = k2[t + q*256];   // 16 KB
    __syncthreads();

    int g   = (blockIdx.x << 5) | (t >> 3);       // 32 gaussians per block
    int seg = t & 7;                              // 8 segments x 256 keys
    unsigned long long ki = sk[g];
    const ulonglong2* sseg = (const ulonglong2*)(sk + (seg << 8));
    int rank = 0;
    #pragma unroll 8
    for (int j = 0; j < 128; ++j) {
        ulonglong2 a = sseg[(j + seg * 17) & 127];   // skew: distinct banks
        rank += (int)(a.x < ki) + (int)(a.y < ki);
    }
    rank += __shfl_xor(rank, 1);
    rank += __shfl_xor(rank, 2);
    rank += __shfl_xor(rank, 4);

    int slot = ((rank & 31) << 6) | (rank >> 5);
    srec[slot * RECF + seg] = rec[g * RECF + seg];
}

// Scan-form compositing:
//   u_k = T_{k-1} * alpha_k,  T = prefix-prod(1-alpha)
//   I   = PI_k (1-u_k) + SUM_k u_k c_k PI_{j>k} (1-u_j)
// One wave = 2 adjacent pixels; lane l owns ranks [32l, 32l+32).
// v-array packed as f16 pairs (32 VGPRs instead of 64).
// launch_bounds(256,2): allow up to 256 VGPR -> NO SPILL (round 9: forcing 4
// waves/EU made the allocator spill 80 MB/launch to scratch; spills cost more
// than the occupancy gains).
__global__ void __launch_bounds__(256, 2)
gs_raster(const float* __restrict__ srec, float* __restrict__ out)
{
    int tid  = threadIdx.x;
    int lane = tid & 63;
    int wave = (blockIdx.x << 2) | (tid >> 6);    // 0..8191
    int p0   = wave * 2;                          // two pixels, same row
    float px0 = (float)(p0 & 127);
    float px1 = px0 + 1.0f;
    float py  = (float)(p0 >> 7);

    float vp[32];                                 // f16x2-packed (u0,u1)
    float P0 = 1.0f, P1 = 1.0f;

    // ---- pass 1: alphas + lane-local prefix products ----
    #pragma unroll
    for (int i = 0; i < 32; ++i) {
        const float* r = srec + (size_t)((i << 6) | lane) * RECF;
        float4 ra = *(const float4*)r;            // mux,muy,A2,B2
        float2 rb = *(const float2*)(r + 4);      // D2,L
        float dy   = py - ra.y;
        float b2dy = ra.w * dy;
        float t2   = fmaf(rb.x * dy, dy, rb.y);
        float dx0  = px0 - ra.x;
        float dx1  = px1 - ra.x;
        float q0 = fmaf(dx0, fmaf(ra.z, dx0, b2dy), t2);
        float q1 = fmaf(dx1, fmaf(ra.z, dx1, b2dy), t2);
        float a0 = fminf(__builtin_amdgcn_exp2f(q0), 0.99f);
        float a1 = fminf(__builtin_amdgcn_exp2f(q1), 0.99f);
        float u0 = P0 * a0;  P0 *= (1.0f - a0);
        float u1 = P1 * a1;  P1 *= (1.0f - a1);
        H2U hp; hp.h2 = __builtin_amdgcn_cvt_pkrtz(u0, u1);
        vp[i] = hp.f;
    }

    // ---- wave exclusive prefix product of lane totals -> T_in per lane ----
    float sp0 = P0, sp1 = P1;
    #pragma unroll
    for (int d = 1; d < 64; d <<= 1) {
        float y0 = __shfl_up(sp0, d);
        float y1 = __shfl_up(sp1, d);
        if (lane >= d) { sp0 *= y0; sp1 *= y1; }
    }
    float e0 = __shfl_up(sp0, 1);
    float e1 = __shfl_up(sp1, 1);
    float Tin0 = (lane == 0) ? 1.0f : e0;
    float Tin1 = (lane == 0) ? 1.0f : e1;

    // ---- pass 2a: lane-local product of (1-u) ----
    float B0 = 1.0f, B1 = 1.0f;
    #pragma unroll
    for (int i = 0; i < 32; ++i) {
        H2U h; h.f = vp[i];
        B0 *= fmaf(-Tin0, (float)h.h2.x, 1.0f);
        B1 *= fmaf(-Tin1, (float)h.h2.y, 1.0f);
    }

    // ---- wave exclusive suffix product -> S_out per lane ----
    float ss0 = B0, ss1 = B1;
    #pragma unroll
    for (int d = 1; d < 64; d <<= 1) {
        float y0 = __shfl_down(ss0, d);
        float y1 = __shfl_down(ss1, d);
        if (lane + d < 64) { ss0 *= y0; ss1 *= y1; }
    }
    float f0 = __shfl_down(ss0, 1);
    float f1 = __shfl_down(ss1, 1);
    float S0 = (lane == 63) ? 1.0f : f0;
    float S1 = (lane == 63) ? 1.0f : f1;

    // ---- pass 2b: descending accumulate  SUM u*c*S ----
    float ar0 = 0.0f, ag0 = 0.0f, ab0 = 0.0f;
    float ar1 = 0.0f, ag1 = 0.0f, ab1 = 0.0f;
    #pragma unroll
    for (int i = 31; i >= 0; --i) {
        const float* r = srec + (size_t)((i << 6) | lane) * RECF;
        float2 cp = *(const float2*)(r + 6);
        unsigned int w6 = __float_as_uint(cp.x);
        unsigned int w7 = __float_as_uint(cp.y);
        float cr = __uint_as_float(w6 << 16);          // bf16 -> f32: 1 shl
        float cg = __uint_as_float(w6 & 0xFFFF0000u);
        float cb = __uint_as_float(w7 << 16);
        H2U h; h.f = vp[i];
        float u0  = Tin0 * (float)h.h2.x;
        float us0 = u0 * S0;
        ar0 = fmaf(us0, cr, ar0); ag0 = fmaf(us0, cg, ag0); ab0 = fmaf(us0, cb, ab0);
        S0 = fmaf(-u0, S0, S0);
        float u1  = Tin1 * (float)h.h2.y;
        float us1 = u1 * S1;
        ar1 = fmaf(us1, cr, ar1); ag1 = fmaf(us1, cg, ag1); ab1 = fmaf(us1, cb, ab1);
        S1 = fmaf(-u1, S1, S1);
    }
    // lane 0's S is now the GLOBAL product PI(1-u) = background coefficient

    // ---- wave sum-reduce the accumulators ----
    #pragma unroll
    for (int d = 1; d < 64; d <<= 1) {
        ar0 += __shfl_xor(ar0, d); ag0 += __shfl_xor(ag0, d); ab0 += __shfl_xor(ab0, d);
        ar1 += __shfl_xor(ar1, d); ag1 += __shfl_xor(ab1*0.0f + ag1, d); ab1 += __shfl_xor(ab1, d);
    }

    if (lane == 0) {
        float* o0 = out + (size_t)p0 * 3;
        o0[0] = fminf(fmaxf(S0 + ar0, 0.0f), 1.0f);
        o0[1] = fminf(fmaxf(S0 + ag0, 0.0f), 1.0f);
        o0[2] = fminf(fmaxf(S0 + ab0, 0.0f), 1.0f);
        o0[3] = fminf(fmaxf(S1 + ar1, 0.0f), 1.0f);
        o0[4] = fminf(fmaxf(S1 + ag1, 0.0f), 1.0f);
        o0[5] = fminf(fmaxf(S1 + ab1, 0.0f), 1.0f);
    }
}

extern "C" void kernel_launch(void* const* d_in, const int* in_sizes, int n_in,
                              void* d_out, int out_size, void* d_ws, size_t ws_size,
                              hipStream_t stream)
{
    const float* means         = (const float*)d_in[0];
    const float* log_scales    = (const float*)d_in[1];
    const float* rotations     = (const float*)d_in[2];
    const float* opacity_logit = (const float*)d_in[3];
    const float* color_pre     = (const float*)d_in[4];
    const float* cam_pos       = (const float*)d_in[5];
    const float* look_at       = (const float*)d_in[6];
    float* out = (float*)d_out;

    char* ws = (char*)d_ws;
    float*              rec  = (float*)(ws);                         // 64 KB
    unsigned long long* keys = (unsigned long long*)(ws + 65536);    // 16 KB
    float*              srec = (float*)(ws + 65536 + 16384);         // 64 KB

    hipLaunchKernelGGL(gs_preprocess, dim3(N_G / 256), dim3(256), 0, stream,
                       means, log_scales, rotations, opacity_logit, color_pre,
                       cam_pos, look_at, rec, keys);
    hipLaunchKernelGGL(gs_rank_scatter, dim3(N_G / 32), dim3(256), 0, stream,
                       keys, rec, srec);
    // 16384 px / 2 px-per-wave = 8192 waves; 4 waves/block -> 2048 blocks
    hipLaunchKernelGGL(gs_raster, dim3(2048), dim3(256), 0, stream,
                       srec, out);
}